// Round 2
// baseline (427.515 us; speedup 1.0000x reference)
//
#include <hip/hip_runtime.h>

#define SLOPE 0.22916666666666666f  // (1/8 + 1/3) / 2
#define ALONE_CAP 8192              // expected alone nodes ~2.3; capacity is overkill-safe

// ---------------------------------------------------------------- CSR build
__global__ __launch_bounds__(256) void count_kernel(const int* __restrict__ dst,
                                                    int* __restrict__ deg, int e) {
    int i = blockIdx.x * 256 + threadIdx.x;
    if (i < e) atomicAdd(&deg[dst[i]], 1);
}

__global__ __launch_bounds__(1024) void scan_kernel(const int* __restrict__ deg,
                                                    int* __restrict__ row_off, int n) {
    __shared__ int wsum[16];
    int tid = threadIdx.x;
    int lane = tid & 63, wid = tid >> 6;
    int base = 0;
    for (int start = 0; start < n; start += 1024) {
        int i = start + tid;
        int v = (i < n) ? deg[i] : 0;
        int x = v;
        #pragma unroll
        for (int off = 1; off < 64; off <<= 1) {
            int y = __shfl_up(x, off, 64);
            if (lane >= off) x += y;
        }
        if (lane == 63) wsum[wid] = x;
        __syncthreads();
        int wbase = 0, total = 0;
        #pragma unroll
        for (int w = 0; w < 16; ++w) {
            int s = wsum[w];
            total += s;
            if (w < wid) wbase += s;
        }
        if (i < n) row_off[i] = base + wbase + x - v;  // exclusive prefix
        base += total;
        __syncthreads();
    }
    if (tid == 0) row_off[n] = base;
}

__global__ __launch_bounds__(256) void scatter_kernel(
    const int* __restrict__ src, const int* __restrict__ dst,
    const int* __restrict__ ety, const int* __restrict__ row_off,
    int* __restrict__ cursor, int2* __restrict__ edges, int e) {
    int i = blockIdx.x * 256 + threadIdx.x;
    if (i < e) {
        int v = dst[i];
        int pos = row_off[v] + atomicAdd(&cursor[v], 1);
        edges[pos] = make_int2(src[i], ety[i]);
    }
}

__global__ __launch_bounds__(256) void flag_kernel(const int* __restrict__ deg,
                                                   int* __restrict__ alone_list,
                                                   int* __restrict__ alone_count, int n) {
    int i = blockIdx.x * 256 + threadIdx.x;
    if (i < n && deg[i] == 0) {
        int p = atomicAdd(alone_count, 1);
        if (p < ALONE_CAP) alone_list[p] = i;
    }
}

// ------------------------------------------------------- per-layer kernels
// S[v] = norm[v] * sum_{e: dst=v} (h[src_e] + rel[etype_e])
__global__ __launch_bounds__(128) void agg_kernel(
    const float* __restrict__ h, const float* __restrict__ rel,
    const float* __restrict__ norm, const int* __restrict__ row_off,
    const int2* __restrict__ edges, float* __restrict__ S, int n) {
    int v = blockIdx.x;
    int t = threadIdx.x;
    int s0 = row_off[v], s1 = row_off[v + 1];
    float acc = 0.f;
    for (int e = s0; e < s1; ++e) {
        int2 ed = edges[e];
        acc += h[ed.x * 128 + t] + rel[ed.y * 128 + t];
    }
    S[v * 128 + t] = acc * norm[v];
}

// out = leaky(S @ Wn + H @ Wl), 128x128 tile per block, 8x8 per thread.
// NOTE: H and out may alias (h1 lives in d_out) — no __restrict__ on them.
// Safe because each block reads H only in its own row range, and all H reads
// complete (barrier-guarded staging) before the epilogue stores.
__global__ __launch_bounds__(256) void gemm_kernel(
    const float* __restrict__ S, const float* H,
    const float* __restrict__ Wn, const float* __restrict__ Wl,
    float* out, int n) {
    __shared__ float Asm[32][132];   // transposed A tile [k][row]
    __shared__ float Wsm[32][128];   // W tile [k][col]
    const int tid = threadIdx.x;
    const int rw = tid >> 4;         // 0..15 -> rows rw*8..rw*8+7
    const int cw = tid & 15;         // 0..15 -> cols cw*8..cw*8+7
    const int row0 = blockIdx.x * 128;

    float acc[8][8];
    #pragma unroll
    for (int i = 0; i < 8; ++i)
        #pragma unroll
        for (int j = 0; j < 8; ++j) acc[i][j] = 0.f;

    #pragma unroll
    for (int pass = 0; pass < 2; ++pass) {
        const float* A = pass ? H : S;
        const float* __restrict__ W = pass ? Wl : Wn;
        for (int k0 = 0; k0 < 128; k0 += 32) {
            __syncthreads();
            // stage A: 128 rows x 32 k, transposed into LDS
            #pragma unroll
            for (int q = 0; q < 4; ++q) {
                int idx = tid + 256 * q;       // 0..1023
                int r = idx >> 3;              // 0..127
                int k4 = (idx & 7) << 2;       // 0,4,..,28
                int gr = row0 + r;
                if (gr >= n) gr = n - 1;
                float4 val = *(const float4*)(A + (size_t)gr * 128 + k0 + k4);
                Asm[k4 + 0][r] = val.x;
                Asm[k4 + 1][r] = val.y;
                Asm[k4 + 2][r] = val.z;
                Asm[k4 + 3][r] = val.w;
            }
            // stage W: 32 k x 128 cols, straight copy
            #pragma unroll
            for (int q = 0; q < 4; ++q) {
                int idx = tid + 256 * q;       // 0..1023
                int kr = idx >> 5;             // 0..31
                int c4 = (idx & 31) << 2;      // 0,4,..,124
                *(float4*)&Wsm[kr][c4] = *(const float4*)(W + (size_t)(k0 + kr) * 128 + c4);
            }
            __syncthreads();
            #pragma unroll
            for (int k = 0; k < 32; ++k) {
                float4 a0 = *(const float4*)&Asm[k][rw * 8];
                float4 a1 = *(const float4*)&Asm[k][rw * 8 + 4];
                float4 w0 = *(const float4*)&Wsm[k][cw * 8];
                float4 w1 = *(const float4*)&Wsm[k][cw * 8 + 4];
                float a[8] = {a0.x, a0.y, a0.z, a0.w, a1.x, a1.y, a1.z, a1.w};
                float w[8] = {w0.x, w0.y, w0.z, w0.w, w1.x, w1.y, w1.z, w1.w};
                #pragma unroll
                for (int i = 0; i < 8; ++i)
                    #pragma unroll
                    for (int j = 0; j < 8; ++j)
                        acc[i][j] += a[i] * w[j];
            }
        }
    }

    #pragma unroll
    for (int i = 0; i < 8; ++i) {
        int r = row0 + rw * 8 + i;
        if (r < n) {
            float o[8];
            #pragma unroll
            for (int j = 0; j < 8; ++j) {
                float v = acc[i][j];
                o[j] = v >= 0.f ? v : v * SLOPE;
            }
            *(float4*)(out + (size_t)r * 128 + cw * 8)     = make_float4(o[0], o[1], o[2], o[3]);
            *(float4*)(out + (size_t)r * 128 + cw * 8 + 4) = make_float4(o[4], o[5], o[6], o[7]);
        }
    }
}

// Snapshot h rows of alone nodes before the GEMM clobbers them (h may alias out).
__global__ __launch_bounds__(128) void save_alone_kernel(
    const float* __restrict__ H, const int* __restrict__ alone_list,
    const int* __restrict__ alone_count, float* __restrict__ asave) {
    int cnt = *alone_count;
    if (cnt > ALONE_CAP) cnt = ALONE_CAP;
    int t = threadIdx.x;
    for (int i = blockIdx.x; i < cnt; i += gridDim.x) {
        int v = alone_list[i];
        asave[i * 128 + t] = H[v * 128 + t];
    }
}

// For alone nodes: out[v] = leaky(hrow @ Wa). hrow comes either directly from a
// non-aliased H (layer 1: ent) or from the snapshot (layer 2).
__global__ __launch_bounds__(128) void fixup_kernel(
    const float* __restrict__ Hrows, const int* __restrict__ row_idx /*null => i*/,
    const float* __restrict__ Wa,
    const int* __restrict__ alone_list, const int* __restrict__ alone_count,
    float* out) {
    int cnt = *alone_count;
    if (cnt > ALONE_CAP) cnt = ALONE_CAP;
    int t = threadIdx.x;
    for (int i = blockIdx.x; i < cnt; i += gridDim.x) {
        int v = alone_list[i];
        int hr = row_idx ? row_idx[i] : i;   // unused trick removed; see launches
        (void)hr;
        const float* hrow = Hrows + (size_t)(row_idx ? v : i) * 128;
        float acc = 0.f;
        for (int k = 0; k < 128; ++k)
            acc += hrow[k] * Wa[k * 128 + t];
        out[v * 128 + t] = acc >= 0.f ? acc : acc * SLOPE;
    }
}

extern "C" void kernel_launch(void* const* d_in, const int* in_sizes, int n_in,
                              void* d_out, int out_size, void* d_ws, size_t ws_size,
                              hipStream_t stream) {
    const float* ent  = (const float*)d_in[0];
    const float* rel  = (const float*)d_in[1];
    const float* norm = (const float*)d_in[2];
    const float* Wn   = (const float*)d_in[3];
    const float* Wl   = (const float*)d_in[4];
    const float* Wa   = (const float*)d_in[5];
    const int*   src  = (const int*)d_in[6];
    const int*   dst  = (const int*)d_in[7];
    const int*   ety  = (const int*)d_in[8];
    float* out = (float*)d_out;

    const int n = in_sizes[2];   // 50000 (norm has N elements)
    const int e = in_sizes[7];   // 500000

    // workspace layout
    char* ws = (char*)d_ws;
    int* deg         = (int*)ws;          // n
    int* cursor      = deg + n;           // n
    int* alone_count = cursor + n;        // 1
    size_t zbytes = (size_t)(2 * n + 1) * sizeof(int);
    size_t p = (zbytes + 255) & ~(size_t)255;
    int* row_off = (int*)(ws + p);        // n+1
    p += (((size_t)(n + 1) * 4) + 255) & ~(size_t)255;
    int* alone_list = (int*)(ws + p);     // ALONE_CAP
    p += (((size_t)ALONE_CAP * 4) + 255) & ~(size_t)255;
    float* asave = (float*)(ws + p);      // ALONE_CAP * 128 floats (4 MB)
    p += (((size_t)ALONE_CAP * 128 * 4) + 255) & ~(size_t)255;
    int2* edges = (int2*)(ws + p);        // e
    p += (((size_t)e * 8) + 255) & ~(size_t)255;
    float* Sbuf = (float*)(ws + p);       // n*128
    float* h1 = out;                      // intermediate h lives in d_out

    const int eb = (e + 255) / 256;
    const int nb = (n + 255) / 256;
    const int gb = (n + 127) / 128;

    hipMemsetAsync(ws, 0, zbytes, stream);
    count_kernel<<<eb, 256, 0, stream>>>(dst, deg, e);
    scan_kernel<<<1, 1024, 0, stream>>>(deg, row_off, n);
    scatter_kernel<<<eb, 256, 0, stream>>>(src, dst, ety, row_off, cursor, edges, e);
    flag_kernel<<<nb, 256, 0, stream>>>(deg, alone_list, alone_count, n);

    // layer 0: h0 = ent -> h1 (in d_out). fixup reads ent (not aliased): row_idx
    // arg non-null selects "index by node id into Hrows".
    agg_kernel<<<n, 128, 0, stream>>>(ent, rel, norm, row_off, edges, Sbuf, n);
    gemm_kernel<<<gb, 256, 0, stream>>>(Sbuf, ent, Wn, Wl, h1, n);
    fixup_kernel<<<16, 128, 0, stream>>>(ent, alone_list /*row_idx=v*/, Wa,
                                         alone_list, alone_count, h1);

    // layer 1: h1 -> out (aliases). Snapshot alone rows BEFORE gemm clobbers h1,
    // then fixup reads the snapshot (row_idx=null => index by i).
    agg_kernel<<<n, 128, 0, stream>>>(h1, rel, norm, row_off, edges, Sbuf, n);
    save_alone_kernel<<<16, 128, 0, stream>>>(h1, alone_list, alone_count, asave);
    gemm_kernel<<<gb, 256, 0, stream>>>(Sbuf, h1, Wn + 16384, Wl + 16384, out, n);
    fixup_kernel<<<16, 128, 0, stream>>>(asave, nullptr, Wa + 16384,
                                         alone_list, alone_count, out);
}